// Round 5
// baseline (58.037 us; speedup 1.0000x reference)
//
#include <hip/hip_runtime.h>

#define NN    8192
#define INF_  256
#define OUTF  64
#define NH    2
#define NE    262144
#define CAP   256
#define DEGS  16          // deg stride (one counter per 64B line)
#define SLOPE 0.2f

typedef __attribute__((ext_vector_type(8))) short short8;
typedef __attribute__((ext_vector_type(4))) float f32x4;
typedef __attribute__((ext_vector_type(2))) long long ll2;

__device__ __forceinline__ unsigned short f2bf(float f) {
  unsigned int u = __float_as_uint(f);
  u += 0x7fffu + ((u >> 16) & 1u);   // round-to-nearest-even
  return (unsigned short)(u >> 16);
}

// blocks 0-127: pack W->Bt bf16 [128][256]; 128-159: zero deg (stride-16);
// block 160: detect int64-vs-int32 edges (odd 32-bit words all zero => int64).
__global__ __launch_bounds__(256) void prep_kernel(const float* __restrict__ W,
                                                   const unsigned int* __restrict__ ei,
                                                   unsigned short* __restrict__ Bt,
                                                   int* __restrict__ deg,
                                                   int* __restrict__ flag) {
  const int b = blockIdx.x, t = threadIdx.x;
  if (b < 128) {
    const int c = b, k = t;
    Bt[c * 256 + k] = f2bf(W[(c >> 6) * (INF_ * OUTF) + k * OUTF + (c & 63)]);
  } else if (b < 160) {
    int4* dp = (int4*)(deg + (size_t)(b - 128) * 4096 + t * 16);
    const int4 z = {0, 0, 0, 0};
    dp[0] = z; dp[1] = z; dp[2] = z; dp[3] = z;
  } else {
    __shared__ int nz;
    if (t == 0) nz = 0;
    __syncthreads();
    if (ei[2u * t + 1u] != 0u) atomicAdd(&nz, 1);
    __syncthreads();
    if (t == 0) *flag = (nz == 0) ? 1 : 0;
  }
}

// GEMM xh = x @ W (M=8192, N=128, K=256), bf16 MFMA; 4 waves share one
// 16-row stripe (2 col-tiles each). s1/s2 written interleaved float2 [n]{h0,h1}.
__global__ __launch_bounds__(256) void xh_mfma_kernel(const float* __restrict__ x,
                                                      const unsigned short* __restrict__ Bt,
                                                      const float* __restrict__ a1,
                                                      const float* __restrict__ a2,
                                                      float* __restrict__ xh,
                                                      float2* __restrict__ s1v,
                                                      float2* __restrict__ s2v) {
  const int t = threadIdx.x;
  const int l = t & 63, w = t >> 6;
  const int lo = l & 15, hi = l >> 4;
  const int n0 = blockIdx.x * 16;
  const int tcb = w * 2;
  __shared__ float p1s[4][16], p2s[4][16];

  const float* xp = x + (size_t)(n0 + lo) * INF_ + hi * 8;
  float4 fr[16];
#pragma unroll
  for (int ks = 0; ks < 8; ++ks) {
    fr[2 * ks]     = *(const float4*)(xp + ks * 32);
    fr[2 * ks + 1] = *(const float4*)(xp + ks * 32 + 4);
  }
  short8 afr[8];
#pragma unroll
  for (int ks = 0; ks < 8; ++ks) {
    short8 a;
    a[0] = (short)f2bf(fr[2 * ks].x);     a[1] = (short)f2bf(fr[2 * ks].y);
    a[2] = (short)f2bf(fr[2 * ks].z);     a[3] = (short)f2bf(fr[2 * ks].w);
    a[4] = (short)f2bf(fr[2 * ks + 1].x); a[5] = (short)f2bf(fr[2 * ks + 1].y);
    a[6] = (short)f2bf(fr[2 * ks + 1].z); a[7] = (short)f2bf(fr[2 * ks + 1].w);
    afr[ks] = a;
  }
  f32x4 acc[2] = {};
#pragma unroll
  for (int ks = 0; ks < 8; ++ks) {
#pragma unroll
    for (int q = 0; q < 2; ++q) {
      const short8 bf = *(const short8*)(Bt + (size_t)((tcb + q) * 16 + lo) * INF_ + ks * 32 + hi * 8);
      acc[q] = __builtin_amdgcn_mfma_f32_16x16x32_bf16(afr[ks], bf, acc[q], 0, 0, 0);
    }
  }
  float a1c[2], a2c[2];
#pragma unroll
  for (int q = 0; q < 2; ++q) {
    const int tc = tcb + q;
    const int h = tc >> 2;
    const int col = (tc * 16 + lo) & 63;
    a1c[q] = a1[h * OUTF + col];
    a2c[q] = a2[h * OUTF + col];
#pragma unroll
    for (int r = 0; r < 4; ++r)
      xh[((size_t)h * NN + n0 + hi * 4 + r) * OUTF + col] = acc[q][r];
  }
#pragma unroll
  for (int r = 0; r < 4; ++r) {
    float p1 = acc[0][r] * a1c[0] + acc[1][r] * a1c[1];
    float p2 = acc[0][r] * a2c[0] + acc[1][r] * a2c[1];
#pragma unroll
    for (int s = 1; s < 16; s <<= 1) {
      p1 += __shfl_xor(p1, s, 64);
      p2 += __shfl_xor(p2, s, 64);
    }
    if (lo == 0) {
      p1s[w][hi * 4 + r] = p1;
      p2s[w][hi * 4 + r] = p2;
    }
  }
  __syncthreads();
  if (t < 16) {
    float2 v1, v2;
    v1.x = p1s[0][t] + p1s[1][t];  v1.y = p1s[2][t] + p1s[3][t];
    v2.x = p2s[0][t] + p2s[1][t];  v2.y = p2s[2][t] + p2s[3][t];
    s1v[n0 + t] = v1;
    s2v[n0 + t] = v2;
  }
}

// Scatter edges into fixed-stride per-src rows; 2 edges per thread.
__global__ __launch_bounds__(256) void edge_kernel(const int* __restrict__ ei,
                                                   const int* __restrict__ flag,
                                                   int* __restrict__ deg,
                                                   int* __restrict__ cols) {
  const int e0 = (blockIdx.x * 256 + threadIdx.x) * 2;
  if (e0 >= NE) return;
  int i0, j0, i1, j1;
  if (*flag) {
    const ll2 a = *(const ll2*)((const long long*)ei + e0);
    const ll2 b = *(const ll2*)((const long long*)ei + NE + e0);
    i0 = (int)a[0]; i1 = (int)a[1]; j0 = (int)b[0]; j1 = (int)b[1];
  } else {
    const int2 a = *(const int2*)(ei + e0);
    const int2 b = *(const int2*)(ei + NE + e0);
    i0 = a.x; i1 = a.y; j0 = b.x; j1 = b.y;
  }
  const int p0 = atomicAdd(&deg[i0 * DEGS], 1);
  if (p0 < CAP) cols[i0 * CAP + p0] = j0;
  const int p1 = atomicAdd(&deg[i1 * DEGS], 1);
  if (p1 < CAP) cols[i1 * CAP + p1] = j1;
}

// One WAVE per (node, head) task: no LDS, no __syncthreads.
// 2048 blocks x 256 thr = 8192 waves; each wave runs 2 tasks (gw, gw+8192).
// Fast path d<=64: edge slot = lane; shfl-scan dedup; softmax in registers;
// gather 4 rows/dwordx4 (row-slot r = lane>>4, feat-quad c4 = lane&15).
__global__ __launch_bounds__(256) void agg_kernel(const float* __restrict__ xh,
                                                  const float2* __restrict__ s1v,
                                                  const float2* __restrict__ s2v,
                                                  const int* __restrict__ deg,
                                                  const int* __restrict__ cols,
                                                  float* __restrict__ out) {
  const int t = threadIdx.x;
  const int w = t >> 6, lane = t & 63;
  const int gw = blockIdx.x * 4 + w;
  const int c4 = lane & 15, r = lane >> 4;

  for (int task = gw; task < NN * NH; task += 8192) {
    const int i = task >> 1, h = task & 1;
    int d0 = deg[i * DEGS];
    if (d0 > CAP) d0 = CAP;
    const int d = __builtin_amdgcn_readfirstlane(d0);
    const float* base = xh + (size_t)h * NN * OUTF;
    f32x4 acc = {0.f, 0.f, 0.f, 0.f};
    float inv;

    if (d == 0) {
      // reference: all-NEG row -> uniform softmax over ALL nodes (never hit at Poisson(32))
      for (int p = r; p < NN; p += 4)
        acc += *(const f32x4*)(base + (size_t)p * OUTF + 4 * c4);
      inv = 1.f / (float)NN;
    } else if (d <= 64) {
      const bool valid = lane < d;
      int j = 0;
      if (valid) j = cols[i * CAP + lane];
      // dedup: mark later occurrences via shfl scan (d iterations, all-register)
      bool dup = false;
      for (int q = 0; q < d; ++q) {
        const int jq = __shfl(j, q, 64);
        dup = dup || ((q < lane) && (jq == j));
      }
      const bool kp = valid && !dup;
      float sc = -1e30f;
      if (kp) {
        const float2 s1i2 = s1v[i];
        const float2 s2j2 = s2v[j];
        sc = (h ? s1i2.y : s1i2.x) + (h ? s2j2.y : s2j2.x);
        sc = (sc >= 0.f) ? sc : SLOPE * sc;
      }
      float m = sc;
#pragma unroll
      for (int s = 32; s > 0; s >>= 1) m = fmaxf(m, __shfl_xor(m, s, 64));
      const float wt = kp ? __expf(sc - m) : 0.f;
      float ds = wt;
#pragma unroll
      for (int s = 32; s > 0; s >>= 1) ds += __shfl_xor(ds, s, 64);
      inv = 1.f / ds;
#pragma unroll 2
      for (int p = 0; p < d; p += 4) {
        const int pr = p + r;
        float ww = __shfl(wt, pr, 64);
        int   jj = __shfl(j,  pr, 64);
        ww = (pr < d) ? ww : 0.f;
        jj = (ww > 0.f) ? jj : 0;
        acc += ww * *(const f32x4*)(base + (size_t)jj * OUTF + 4 * c4);
      }
    } else {
      // storage-free slow path (insurance; max Poisson(32) degree ~57 < 64)
      const float2 s1i2 = s1v[i];
      const float s1i = h ? s1i2.y : s1i2.x;
      float m = -1e30f;
      for (int p = lane; p < d; p += 64) {
        const int j = cols[i * CAP + p];
        bool dup = false;
        for (int q = 0; q < p; ++q)
          if (cols[i * CAP + q] == j) { dup = true; break; }
        if (!dup) {
          const float2 s2j2 = s2v[j];
          float sc = s1i + (h ? s2j2.y : s2j2.x);
          sc = (sc >= 0.f) ? sc : SLOPE * sc;
          m = fmaxf(m, sc);
        }
      }
#pragma unroll
      for (int s = 32; s > 0; s >>= 1) m = fmaxf(m, __shfl_xor(m, s, 64));
      float ds = 0.f;
      for (int p = lane; p < d; p += 64) {
        const int j = cols[i * CAP + p];
        bool dup = false;
        for (int q = 0; q < p; ++q)
          if (cols[i * CAP + q] == j) { dup = true; break; }
        if (!dup) {
          const float2 s2j2 = s2v[j];
          float sc = s1i + (h ? s2j2.y : s2j2.x);
          sc = (sc >= 0.f) ? sc : SLOPE * sc;
          ds += __expf(sc - m);
        }
      }
#pragma unroll
      for (int s = 32; s > 0; s >>= 1) ds += __shfl_xor(ds, s, 64);
      inv = 1.f / ds;
      for (int p = 0; p < d; ++p) {
        const int j = __shfl((lane == (p & 63)) ? cols[i * CAP + p] : 0, p & 63, 64);
        bool dup = false;
        for (int q = 0; q < p; ++q)
          if (cols[i * CAP + q] == j) { dup = true; break; }
        if (!dup) {
          const float2 s2j2 = s2v[j];
          float sc = s1i + (h ? s2j2.y : s2j2.x);
          sc = (sc >= 0.f) ? sc : SLOPE * sc;
          const float ww = __expf(sc - m);
          acc += ww * *(const f32x4*)(base + (size_t)j * OUTF + 4 * c4);
        }
      }
    }
#pragma unroll
    for (int c = 0; c < 4; ++c) {
      acc[c] += __shfl_xor(acc[c], 16, 64);
      acc[c] += __shfl_xor(acc[c], 32, 64);
    }
    if (lane < 16) {
      float4 o;
      o.x = acc[0] * inv; o.y = acc[1] * inv; o.z = acc[2] * inv; o.w = acc[3] * inv;
      *(float4*)(out + (size_t)i * (NH * OUTF) + h * OUTF + 4 * lane) = o;
    }
  }
}

extern "C" void kernel_launch(void* const* d_in, const int* in_sizes, int n_in,
                              void* d_out, int out_size, void* d_ws, size_t ws_size,
                              hipStream_t stream) {
  const float* x  = (const float*)d_in[0];
  const int*   ei = (const int*)d_in[1];
  const float* W  = (const float*)d_in[2];
  const float* a1 = (const float*)d_in[3];
  const float* a2 = (const float*)d_in[4];
  float* out = (float*)d_out;

  char* ws = (char*)d_ws;
  float*          xh  = (float*)(ws);                               // 4 MB
  float2*         s1v = (float2*)(ws + (4u << 20));                 // 64 KB
  float2*         s2v = (float2*)(ws + (4u << 20) + (64u << 10));   // 64 KB
  int*            deg = (int*)  (ws + (4u << 20) + (128u << 10));   // 512 KB (stride 16)
  int*            cols= (int*)  (ws + (5u << 20));                  // 8 MB
  unsigned short* Bt  = (unsigned short*)(ws + (13u << 20));        // 64 KB
  int*            flag= (int*)  (ws + (13u << 20) + (64u << 10));

  prep_kernel<<<161, 256, 0, stream>>>(W, (const unsigned int*)ei, Bt, deg, flag);
  xh_mfma_kernel<<<NN / 16, 256, 0, stream>>>(x, Bt, a1, a2, xh, s1v, s2v);
  edge_kernel<<<NE / 512, 256, 0, stream>>>(ei, flag, deg, cols);
  agg_kernel<<<2048, 256, 0, stream>>>(xh, s1v, s2v, deg, cols, out);
}